// Round 2
// baseline (5082.164 us; speedup 1.0000x reference)
//
#include <hip/hip_runtime.h>
#include <hip/hip_bf16.h>
#include <stdint.h>

#define T_STEPS 64
#define BATCH   512
#define SDIM    10
#define HDIM    1024
#define GDIM    4096   // 4*H

typedef __attribute__((ext_vector_type(8))) short bf16x8;
typedef __attribute__((ext_vector_type(4))) float f32x4;

#define MFMA16(a,b,c) __builtin_amdgcn_mfma_f32_16x16x32_bf16(a,b,c,0,0,0)

__device__ __forceinline__ float sigmoidf_(float x) { return 1.0f / (1.0f + __expf(-x)); }
__device__ __forceinline__ float tanhf_(float x) {
    x = fminf(15.0f, fmaxf(-15.0f, x));
    float e = __expf(2.0f * x);
    return (e - 1.0f) / (e + 1.0f);
}

// ---------------------------------------------------------------------------
// Setup: W_hh -> bf16; W_out -> bf16 transposed+padded [16][1024]; zero flags.
// ---------------------------------------------------------------------------
__global__ void setup_kernel(const float* __restrict__ W_hh,
                             const float* __restrict__ W_out,
                             __hip_bfloat16* __restrict__ whh_bf,
                             __hip_bfloat16* __restrict__ wot_bf,
                             int* __restrict__ flags) {
    int idx = blockIdx.x * blockDim.x + threadIdx.x;
    int stride = gridDim.x * blockDim.x;
    for (int i = idx; i < GDIM * HDIM; i += stride)
        whh_bf[i] = __float2bfloat16(W_hh[i]);
    for (int i = idx; i < 16 * HDIM; i += stride) {
        int n = i >> 10, k = i & 1023;
        wot_bf[i] = (n < SDIM) ? __float2bfloat16(W_out[k * SDIM + n]) : __float2bfloat16(0.0f);
    }
    if (idx < 256) flags[idx] = 0;
}

// ---------------------------------------------------------------------------
// Weq[s][n] = sum_k W_in[s][k] * W_ih[n][k]  (fp32 input-path folding)
// beq[n]   = b_ih[n] + b_hh[n] + sum_k b_in[k] * W_ih[n][k]
// ---------------------------------------------------------------------------
__global__ void weq_kernel(const float* __restrict__ W_in,
                           const float* __restrict__ W_ih,
                           const float* __restrict__ b_in,
                           const float* __restrict__ b_ih,
                           const float* __restrict__ b_hh,
                           float* __restrict__ Weq,
                           float* __restrict__ beq) {
    int gw = (blockIdx.x * blockDim.x + threadIdx.x) >> 6;
    int lane = threadIdx.x & 63;
    if (gw >= GDIM) return;
    float acc[SDIM + 1];
#pragma unroll
    for (int s = 0; s <= SDIM; s++) acc[s] = 0.0f;
    for (int it = 0; it < HDIM / 64; ++it) {
        int k = lane + it * 64;
        float w = W_ih[gw * HDIM + k];
#pragma unroll
        for (int s = 0; s < SDIM; s++) acc[s] += w * W_in[s * HDIM + k];
        acc[SDIM] += w * b_in[k];
    }
#pragma unroll
    for (int s = 0; s <= SDIM; s++) {
        float v = acc[s];
        for (int off = 32; off > 0; off >>= 1) v += __shfl_down(v, off);
        acc[s] = v;
    }
    if (lane == 0) {
#pragma unroll
        for (int s = 0; s < SDIM; s++) Weq[s * GDIM + gw] = acc[s];
        beq[gw] = acc[SDIM] + b_ih[gw] + b_hh[gw];
    }
}

// ---------------------------------------------------------------------------
// Persistent LSTM: 256 blocks x 512 threads, all 64 timesteps in one launch.
// Block (m, nb): rows m*128..+127 of batch, h-cols nb*16..+15 (x 4 gates = 64 N).
// Waves: 8 = 4m x 2n, wave tile 32x32. B quarter-K in regs, 3/4-K in LDS (once).
// m-group barrier (64 blocks) between steps via device-scope atomics.
// ---------------------------------------------------------------------------
__launch_bounds__(512, 2)
__global__ void lstm_persistent(const float* __restrict__ inputs,
                                const float* __restrict__ Weq,
                                const float* __restrict__ beq,
                                const __hip_bfloat16* __restrict__ whh,
                                __hip_bfloat16* __restrict__ hs,
                                int* __restrict__ flags) {
    __shared__ __align__(16) unsigned char sB[98304];  // B rows [64][1536B] (k=256..1023)
    __shared__ __align__(16) unsigned char sA[32768];  // A ktile dbuf 2x16KB; [0:16K] reused for gate exchange
    __shared__ float s_inp[1280];                      // inputs tile [128][10]

    const int tid = threadIdx.x;
    const int bid = blockIdx.x;
    const int xcd = bid & 7, idx = bid >> 3;
    const int nb = xcd * 8 + (idx & 7);   // n-block 0..63 (XCD-partitioned B cols)
    const int mg = idx >> 3;              // m-group 0..3
    const int m0 = mg * 128;
    const int h0 = nb * 16;

    const int wv = tid >> 6, lane = tid & 63;
    const int wm = wv >> 1, wn = wv & 1;
    const int lr = lane & 15, lk = lane >> 4;
    const int hf = tid & 15;

    // ---- one-time: B upper 3/4-K into LDS (k = 256..1023), XOR-swizzled ----
#pragma unroll
    for (int i = 0; i < 12; i++) {
        int q = tid + i * 512;
        int row = q / 96, col = q % 96;
        int grow = (row >> 4) * HDIM + h0 + (row & 15);
        uint4 v = *(const uint4*)(whh + grow * HDIM + 256 + col * 8);
        *(uint4*)(sB + row * 1536 + ((col * 16) ^ ((row & 7) << 4))) = v;
    }

    // ---- one-time: B quarter-K into regs (kchunks 0..7 => k 0..255) ----
    bf16x8 breg[2][8];
#pragma unroll
    for (int nn = 0; nn < 2; nn++) {
        int row = wn * 32 + nn * 16 + lr;
        int grow = (row >> 4) * HDIM + h0 + (row & 15);
        const __hip_bfloat16* bse = whh + grow * HDIM + lk * 8;
#pragma unroll
        for (int kk = 0; kk < 8; kk++)
            breg[nn][kk] = *(const bf16x8*)(bse + kk * 32);
    }

    // ---- one-time: input-path coefficients into regs ----
    float wq[4][SDIM], bq[4];
#pragma unroll
    for (int g = 0; g < 4; g++) {
        bq[g] = beq[g * HDIM + h0 + hf];
#pragma unroll
        for (int s = 0; s < SDIM; s++)
            wq[g][s] = Weq[s * GDIM + g * HDIM + h0 + hf];
    }

    // ---- precomputed LDS offsets ----
    int aoff[2][2], boff[2][2];
#pragma unroll
    for (int mm = 0; mm < 2; mm++) {
        int row = wm * 32 + mm * 16 + lr;
#pragma unroll
        for (int kk = 0; kk < 2; kk++)
            aoff[mm][kk] = row * 128 + ((kk * 64 + lk * 16) ^ ((row & 7) << 4));
    }
#pragma unroll
    for (int nn = 0; nn < 2; nn++) {
        int row = wn * 32 + nn * 16 + lr;
#pragma unroll
        for (int kk = 0; kk < 2; kk++)
            boff[nn][kk] = row * 1536 + ((kk * 64 + lk * 16) ^ ((row & 7) << 4));
    }
    int s_row[2], s_wo[2], s_ce[2];
#pragma unroll
    for (int i = 0; i < 2; i++) {
        int q = tid + i * 512;
        s_row[i] = q >> 3;
        s_ce[i] = (q & 7) * 8;
        s_wo[i] = s_row[i] * 128 + (((q & 7) * 16) ^ ((s_row[i] & 7) << 4));
    }

    float c_reg[4] = {0.f, 0.f, 0.f, 0.f};
    int* flag_base = flags + mg * T_STEPS;

    // ================= t = 0 (h0 = 0: gates = input path only) =================
    for (int i = tid; i < 1280; i += 512)
        s_inp[i] = inputs[0 * (BATCH * SDIM) + m0 * SDIM + i];
    __syncthreads();
#pragma unroll
    for (int j = 0; j < 4; j++) {
        int bl = (tid >> 4) + j * 32;
        float xv[SDIM];
#pragma unroll
        for (int s2 = 0; s2 < 5; s2++) {
            float2 v = *(const float2*)&s_inp[bl * 10 + s2 * 2];
            xv[s2 * 2] = v.x; xv[s2 * 2 + 1] = v.y;
        }
        float pre[4];
#pragma unroll
        for (int g = 0; g < 4; g++) {
            float a = bq[g];
#pragma unroll
            for (int s = 0; s < SDIM; s++) a += xv[s] * wq[g][s];
            pre[g] = a;
        }
        float ig = sigmoidf_(pre[0]);
        float gg = tanhf_(pre[2]);
        float og = sigmoidf_(pre[3]);
        float cn = ig * gg;
        c_reg[j] = cn;
        hs[(0 * BATCH + m0 + bl) * HDIM + h0 + hf] = __float2bfloat16(og * tanhf_(cn));
    }
    // m-group barrier t=0
    {
        __threadfence(); __syncthreads();
        if (tid == 0) {
            __hip_atomic_fetch_add(&flag_base[0], 1, __ATOMIC_RELEASE, __HIP_MEMORY_SCOPE_AGENT);
            while (__hip_atomic_load(&flag_base[0], __ATOMIC_ACQUIRE, __HIP_MEMORY_SCOPE_AGENT) < 64) {}
        }
        __syncthreads(); __threadfence();
    }

    // ================= t = 1..63 =================
    for (int t = 1; t < T_STEPS; t++) {
        const __hip_bfloat16* hprev = hs + (size_t)(t - 1) * BATCH * HDIM;

        // stage inputs tile (read at epilogue; ordered by K-loop barriers)
        for (int i = tid; i < 1280; i += 512)
            s_inp[i] = inputs[t * (BATCH * SDIM) + m0 * SDIM + i];

        // stage A ktile 0 into buf0
#pragma unroll
        for (int i = 0; i < 2; i++) {
            uint4 v = *(const uint4*)(hprev + (m0 + s_row[i]) * HDIM + s_ce[i]);
            *(uint4*)(sA + s_wo[i]) = v;
        }
        __syncthreads();

        f32x4 acc[2][2];
#pragma unroll
        for (int mm = 0; mm < 2; mm++)
#pragma unroll
            for (int nn = 0; nn < 2; nn++) acc[mm][nn] = (f32x4){0.f, 0.f, 0.f, 0.f};

        uint4 pref[2];
        // ---- ktiles 0..3: B from registers (fully unrolled for static breg idx) ----
#pragma unroll
        for (int kt = 0; kt < 4; kt++) {
#pragma unroll
            for (int i = 0; i < 2; i++)
                pref[i] = *(const uint4*)(hprev + (m0 + s_row[i]) * HDIM + (kt + 1) * 64 + s_ce[i]);
            const unsigned char* A = sA + (kt & 1) * 16384;
#pragma unroll
            for (int kk = 0; kk < 2; kk++) {
                bf16x8 a0 = *(const bf16x8*)(A + aoff[0][kk]);
                bf16x8 a1 = *(const bf16x8*)(A + aoff[1][kk]);
                acc[0][0] = MFMA16(a0, breg[0][kt * 2 + kk], acc[0][0]);
                acc[0][1] = MFMA16(a0, breg[1][kt * 2 + kk], acc[0][1]);
                acc[1][0] = MFMA16(a1, breg[0][kt * 2 + kk], acc[1][0]);
                acc[1][1] = MFMA16(a1, breg[1][kt * 2 + kk], acc[1][1]);
            }
            unsigned char* W = sA + ((kt & 1) ^ 1) * 16384;
            *(uint4*)(W + s_wo[0]) = pref[0];
            *(uint4*)(W + s_wo[1]) = pref[1];
            __syncthreads();
        }
        // ---- ktiles 4..15: B from LDS ----
        for (int kt = 4; kt < 16; kt++) {
            if (kt < 15) {
#pragma unroll
                for (int i = 0; i < 2; i++)
                    pref[i] = *(const uint4*)(hprev + (m0 + s_row[i]) * HDIM + (kt + 1) * 64 + s_ce[i]);
            }
            const unsigned char* A = sA + (kt & 1) * 16384;
            const unsigned char* Bb = sB + (kt - 4) * 128;
#pragma unroll
            for (int kk = 0; kk < 2; kk++) {
                bf16x8 a0 = *(const bf16x8*)(A + aoff[0][kk]);
                bf16x8 a1 = *(const bf16x8*)(A + aoff[1][kk]);
                bf16x8 b0 = *(const bf16x8*)(Bb + boff[0][kk]);
                bf16x8 b1 = *(const bf16x8*)(Bb + boff[1][kk]);
                acc[0][0] = MFMA16(a0, b0, acc[0][0]);
                acc[0][1] = MFMA16(a0, b1, acc[0][1]);
                acc[1][0] = MFMA16(a1, b0, acc[1][0]);
                acc[1][1] = MFMA16(a1, b1, acc[1][1]);
            }
            if (kt < 15) {
                unsigned char* W = sA + ((kt & 1) ^ 1) * 16384;
                *(uint4*)(W + s_wo[0]) = pref[0];
                *(uint4*)(W + s_wo[1]) = pref[1];
            }
            __syncthreads();
        }

        // ---- epilogue: 2 exchange rounds through sA[0:16K] ----
        float2* X = (float2*)sA;
#pragma unroll
        for (int mm = 0; mm < 2; mm++) {
#pragma unroll
            for (int r = 0; r < 4; r++) {
                int row64 = wm * 16 + lk * 4 + r;
                X[(row64 * 16 + lr) * 2 + wn] = make_float2(acc[mm][0][r], acc[mm][1][r]);
            }
            __syncthreads();
            if (((tid >> 8) & 1) == mm) {
#pragma unroll
                for (int j = 0; j < 4; j++) {
                    int bl = (tid >> 4) + j * 32;
                    int row64 = ((bl >> 5) << 4) + (bl & 15);
                    float4 g4 = *(float4*)&X[(row64 * 16 + hf) * 2];
                    float xv[SDIM];
#pragma unroll
                    for (int s2 = 0; s2 < 5; s2++) {
                        float2 v = *(const float2*)&s_inp[bl * 10 + s2 * 2];
                        xv[s2 * 2] = v.x; xv[s2 * 2 + 1] = v.y;
                    }
                    float pre[4] = {g4.x, g4.y, g4.z, g4.w};
#pragma unroll
                    for (int g = 0; g < 4; g++) {
                        float a = pre[g] + bq[g];
#pragma unroll
                        for (int s = 0; s < SDIM; s++) a += xv[s] * wq[g][s];
                        pre[g] = a;
                    }
                    float ig = sigmoidf_(pre[0]);
                    float fg = sigmoidf_(pre[1]);
                    float gg = tanhf_(pre[2]);
                    float og = sigmoidf_(pre[3]);
                    float cn = fg * c_reg[j] + ig * gg;
                    c_reg[j] = cn;
                    hs[((size_t)t * BATCH + m0 + bl) * HDIM + h0 + hf] =
                        __float2bfloat16(og * tanhf_(cn));
                }
            }
            __syncthreads();
        }

        // ---- m-group barrier (skip after last step) ----
        if (t < T_STEPS - 1) {
            __threadfence(); __syncthreads();
            if (tid == 0) {
                __hip_atomic_fetch_add(&flag_base[t], 1, __ATOMIC_RELEASE, __HIP_MEMORY_SCOPE_AGENT);
                while (__hip_atomic_load(&flag_base[t], __ATOMIC_ACQUIRE, __HIP_MEMORY_SCOPE_AGENT) < 64) {}
            }
            __syncthreads(); __threadfence();
        }
    }
}

// ---------------------------------------------------------------------------
// out[b,t,s] = hs[t,b,:] @ W_out + b_out  via MFMA (N padded 10->16).
// 256 blocks x 256 thr (4 waves); each wave: 2 strips of 16 rows, K=1024.
// ---------------------------------------------------------------------------
__launch_bounds__(256)
__global__ void out_mfma(const __hip_bfloat16* __restrict__ hs,
                         const __hip_bfloat16* __restrict__ wot, // [16][1024]
                         const float* __restrict__ b_out,
                         float* __restrict__ out) {
    __shared__ __align__(16) unsigned char sW[32768];
    const int tid = threadIdx.x, lane = tid & 63, wv = tid >> 6;
    const int lr = lane & 15, lk = lane >> 4;
#pragma unroll
    for (int i = 0; i < 8; i++) {
        int q = tid + i * 256;
        int row = q >> 7, col = q & 127;
        uint4 v = *(const uint4*)(wot + row * 1024 + col * 8);
        *(uint4*)(sW + row * 2048 + ((col * 16) ^ ((row & 7) << 4))) = v;
    }
    float bo = (lr < SDIM) ? b_out[lr] : 0.0f;
    __syncthreads();
    const int sw = (lr & 7) << 4;
    const int brow = lr * 2048;
#pragma unroll
    for (int s2 = 0; s2 < 2; s2++) {
        int strip = blockIdx.x * 8 + wv * 2 + s2;
        const __hip_bfloat16* Ab = hs + (size_t)(strip * 16 + lr) * 1024 + lk * 8;
        f32x4 acc = {0.f, 0.f, 0.f, 0.f};
        for (int kc = 0; kc < 32; kc++) {
            bf16x8 a = *(const bf16x8*)(Ab + kc * 32);
            bf16x8 b = *(const bf16x8*)(sW + brow + ((kc * 64 + lk * 16) ^ sw));
            acc = MFMA16(a, b, acc);
        }
        if (lr < SDIM) {
#pragma unroll
            for (int r = 0; r < 4; r++) {
                int grow = strip * 16 + lk * 4 + r;
                out[(grow & 511) * (T_STEPS * SDIM) + (grow >> 9) * SDIM + lr] = acc[r] + bo;
            }
        }
    }
}

// ---------------------------------------------------------------------------
extern "C" void kernel_launch(void* const* d_in, const int* in_sizes, int n_in,
                              void* d_out, int out_size, void* d_ws, size_t ws_size,
                              hipStream_t stream) {
    const float* inputs = (const float*)d_in[0];
    const float* W_in   = (const float*)d_in[1];
    const float* b_in   = (const float*)d_in[2];
    const float* W_ih   = (const float*)d_in[3];
    const float* W_hh   = (const float*)d_in[4];
    const float* b_ih   = (const float*)d_in[5];
    const float* b_hh   = (const float*)d_in[6];
    const float* W_out  = (const float*)d_in[7];
    const float* b_out  = (const float*)d_in[8];
    float* out = (float*)d_out;

    uint8_t* ws = (uint8_t*)d_ws;
    __hip_bfloat16* whh_bf = (__hip_bfloat16*)(ws);                    //  8 MB
    __hip_bfloat16* hs     = (__hip_bfloat16*)(ws + (8u << 20));       // 64 MB
    __hip_bfloat16* wot_bf = (__hip_bfloat16*)(ws + (72u << 20));      // 32 KB
    float*          Weq    = (float*)(ws + (72u << 20) + 65536);       // 160 KB
    float*          beq    = (float*)(ws + (72u << 20) + 65536 + 163840);
    int*            flags  = (int*)(ws + (72u << 20) + 65536 + 163840 + 16384);

    setup_kernel<<<2048, 256, 0, stream>>>(W_hh, W_out, whh_bf, wot_bf, flags);
    weq_kernel<<<1024, 256, 0, stream>>>(W_in, W_ih, b_in, b_ih, b_hh, Weq, beq);
    lstm_persistent<<<256, 512, 0, stream>>>(inputs, Weq, beq, whh_bf, hs, flags);
    out_mfma<<<256, 256, 0, stream>>>(hs, wot_bf, b_out, out);
}

// Round 3
// 1230.553 us; speedup vs baseline: 4.1300x; 4.1300x over previous
//
#include <hip/hip_runtime.h>
#include <hip/hip_bf16.h>
#include <stdint.h>

#define T_STEPS 64
#define BATCH   512
#define SDIM    10
#define HDIM    1024
#define GDIM    4096   // 4*H

typedef __attribute__((ext_vector_type(8))) short bf16x8;
typedef __attribute__((ext_vector_type(4))) float f32x4;

#define MFMA16(a,b,c) __builtin_amdgcn_mfma_f32_16x16x32_bf16(a,b,c,0,0,0)

__device__ __forceinline__ float sigmoidf_(float x) { return 1.0f / (1.0f + __expf(-x)); }
__device__ __forceinline__ float tanhf_(float x) {
    x = fminf(15.0f, fmaxf(-15.0f, x));
    float e = __expf(2.0f * x);
    return (e - 1.0f) / (e + 1.0f);
}

// async global->LDS, 16B per lane; LDS dest is wave-uniform base + lane*16
__device__ __forceinline__ void gload16(const void* g, void* l) {
    __builtin_amdgcn_global_load_lds(
        (const __attribute__((address_space(1))) unsigned int*)g,
        (__attribute__((address_space(3))) unsigned int*)l, 16, 0, 0);
}

// ---------------------------------------------------------------------------
// Setup: W_hh -> bf16 ([4H][H], K contiguous); W_out -> bf16 transposed+padded
// [16][1024].
// ---------------------------------------------------------------------------
__global__ void setup_kernel(const float* __restrict__ W_hh,
                             const float* __restrict__ W_out,
                             __hip_bfloat16* __restrict__ whh_bf,
                             __hip_bfloat16* __restrict__ wot_bf) {
    int idx = blockIdx.x * blockDim.x + threadIdx.x;
    int stride = gridDim.x * blockDim.x;
    for (int i = idx; i < GDIM * HDIM; i += stride)
        whh_bf[i] = __float2bfloat16(W_hh[i]);
    for (int i = idx; i < 16 * HDIM; i += stride) {
        int n = i >> 10, k = i & 1023;
        wot_bf[i] = (n < SDIM) ? __float2bfloat16(W_out[k * SDIM + n]) : __float2bfloat16(0.0f);
    }
}

// ---------------------------------------------------------------------------
// Weq[s][n] = sum_k W_in[s][k] * W_ih[n][k]   (fp32 input-path folding)
// beq[n]   = b_ih[n] + b_hh[n] + sum_k b_in[k] * W_ih[n][k]
// 256 blocks x 256 thr; W_in + b_in staged in LDS once per block.
// ---------------------------------------------------------------------------
__launch_bounds__(256)
__global__ void weq_kernel(const float* __restrict__ W_in,
                           const float* __restrict__ W_ih,
                           const float* __restrict__ b_in,
                           const float* __restrict__ b_ih,
                           const float* __restrict__ b_hh,
                           float* __restrict__ Weq,
                           float* __restrict__ beq) {
    __shared__ float sWin[SDIM * HDIM];  // 40 KB
    __shared__ float sbin[HDIM];         //  4 KB
    const int tid = threadIdx.x;
    for (int i = tid; i < SDIM * HDIM; i += 256) sWin[i] = W_in[i];
    for (int i = tid; i < HDIM; i += 256) sbin[i] = b_in[i];
    __syncthreads();
    const int wv = tid >> 6, lane = tid & 63;
#pragma unroll
    for (int j = 0; j < 4; ++j) {
        int n = blockIdx.x * 16 + wv * 4 + j;
        float acc[SDIM + 1];
#pragma unroll
        for (int s = 0; s <= SDIM; s++) acc[s] = 0.0f;
        for (int it = 0; it < HDIM / 64; ++it) {
            int k = lane + it * 64;
            float wih = W_ih[n * HDIM + k];
#pragma unroll
            for (int s = 0; s < SDIM; s++) acc[s] += wih * sWin[s * HDIM + k];
            acc[SDIM] += wih * sbin[k];
        }
#pragma unroll
        for (int s = 0; s <= SDIM; s++) {
            float v = acc[s];
            for (int off = 32; off > 0; off >>= 1) v += __shfl_down(v, off);
            acc[s] = v;
        }
        if (lane == 0) {
#pragma unroll
            for (int s = 0; s < SDIM; s++) Weq[s * GDIM + n] = acc[s];
            beq[n] = acc[SDIM] + b_ih[n] + b_hh[n];
        }
    }
}

// ---------------------------------------------------------------------------
// t = 0: h_prev = 0, gates = input path only. One thread per (b, h).
// ---------------------------------------------------------------------------
__launch_bounds__(256)
__global__ void t0_kernel(const float* __restrict__ inputs,
                          const float* __restrict__ Weq,
                          const float* __restrict__ beq,
                          __hip_bfloat16* __restrict__ hs,
                          float* __restrict__ c_buf) {
    int gidx = blockIdx.x * 256 + threadIdx.x;   // 0 .. 512*1024-1
    int b = gidx >> 10, h = gidx & 1023;
    float xv[SDIM];
#pragma unroll
    for (int s = 0; s < SDIM; s++) xv[s] = inputs[b * SDIM + s];
    float pre[4];
#pragma unroll
    for (int g = 0; g < 4; ++g) {
        float a = beq[g * HDIM + h];
#pragma unroll
        for (int s = 0; s < SDIM; s++) a += xv[s] * Weq[s * GDIM + g * HDIM + h];
        pre[g] = a;
    }
    float ig = sigmoidf_(pre[0]);
    float gg = tanhf_(pre[2]);
    float og = sigmoidf_(pre[3]);
    float cn = ig * gg;
    c_buf[gidx] = cn;
    hs[gidx] = __float2bfloat16(og * tanhf_(cn));
}

// ---------------------------------------------------------------------------
// One LSTM timestep. BM=64 batch rows x 16 h (x 4 gates = 64 N). 256 thr,
// 4 waves; wave tile 16 rows x 64 cols (4 gate-frags of same 16 h) so each
// lane holds all 4 gates of one (row, h): no gate exchange, c/h in-lane.
// Staging: global_load_lds width-16, pre-swizzled source (chunk ^= row&7),
// XOR-swizzled ds_read_b128; A/B double-buffered, 1 barrier per k-tile.
// Grid 512 = 8 m-blocks x 64 n-blocks, XCD-major n mapping (W_hh stripe and
// c slice stay L2-resident per XCD across all 64 launches).
// ---------------------------------------------------------------------------
__launch_bounds__(256, 2)
__global__ void step_kernel(const float* __restrict__ inputs,
                            const float* __restrict__ Weq,
                            const float* __restrict__ beq,
                            const __hip_bfloat16* __restrict__ whh,
                            __hip_bfloat16* __restrict__ hs,
                            float* __restrict__ c_buf,
                            int t) {
    __shared__ __align__(16) unsigned char sA[16384];  // 2 x 8 KB (64 rows x 128 B)
    __shared__ __align__(16) unsigned char sB[16384];  // 2 x 8 KB
    __shared__ float s_inp[BATCH / 8 * SDIM / 8 * 8];  // 64*10 = 640 f32
    __shared__ float s_wq[64 * 11];                    // per n-col: wq[10], bq

    const int tid = threadIdx.x;
    const int w = tid >> 6, lane = tid & 63;
    const int lr = lane & 15, lk = lane >> 4;

    const int bid = blockIdx.x;
    const int nb = (bid & 7) * 8 + ((bid >> 3) & 7);  // 0..63, XCD-major
    const int mb = bid >> 6;                          // 0..7
    const int m0 = mb * 64;
    const int h0 = nb * 16;

    const __hip_bfloat16* hprev = hs + (size_t)(t - 1) * BATCH * HDIM;

    // ---- per-lane staging sources (chunk XOR-preswizzle) ----
    const int srow = lane >> 3, c8 = lane & 7;
    const __hip_bfloat16* aSrc[2];
    const __hip_bfloat16* bSrc[2];
#pragma unroll
    for (int j = 0; j < 2; j++) {
        int row = w * 16 + j * 8 + srow;
        aSrc[j] = hprev + (size_t)(m0 + row) * HDIM + ((c8 ^ (row & 7)) << 3);
        int g = row >> 4, hh = row & 15;
        bSrc[j] = whh + (size_t)(g * HDIM + h0 + hh) * HDIM + ((c8 ^ (row & 7)) << 3);
    }

    // ---- stage inputs tile + Weq slice (read only in epilogue) ----
    for (int i = tid; i < 640; i += 256)
        s_inp[i] = inputs[(t * BATCH + m0) * SDIM + i];
    for (int i = tid; i < 704; i += 256) {
        int nloc = i / 11, s = i - nloc * 11;  // nloc = g*16+hh
        int n = (nloc >> 4) * HDIM + h0 + (nloc & 15);
        s_wq[i] = (s < SDIM) ? Weq[s * GDIM + n] : beq[n];
    }

    // ---- prologue: stage k-tile 0 into buf 0 ----
    {
        unsigned char* la = sA + w * 2048;
        unsigned char* lb = sB + w * 2048;
        gload16(aSrc[0], la);
        gload16(aSrc[1], la + 1024);
        gload16(bSrc[0], lb);
        gload16(bSrc[1], lb + 1024);
    }
    __syncthreads();

    f32x4 acc[4];
#pragma unroll
    for (int g = 0; g < 4; g++) acc[g] = (f32x4){0.f, 0.f, 0.f, 0.f};

    const int rowA = w * 16 + lr;
    const int aswz = (rowA & 7) << 4;

    for (int kt = 0; kt < 16; ++kt) {
        const int buf = (kt & 1) << 13;
        if (kt < 15) {  // issue next tile's DMA before compute
            const int ko = (kt + 1) * 64;
            const int nbuf = buf ^ 8192;
            unsigned char* la = sA + nbuf + w * 2048;
            unsigned char* lb = sB + nbuf + w * 2048;
            gload16(aSrc[0] + ko, la);
            gload16(aSrc[1] + ko, la + 1024);
            gload16(bSrc[0] + ko, lb);
            gload16(bSrc[1] + ko, lb + 1024);
        }
        const unsigned char* Ab = sA + buf;
        const unsigned char* Bb = sB + buf;
#pragma unroll
        for (int kk = 0; kk < 2; ++kk) {
            const int byteoff = kk * 64 + lk * 16;
            bf16x8 a = *(const bf16x8*)(Ab + rowA * 128 + (byteoff ^ aswz));
#pragma unroll
            for (int g = 0; g < 4; ++g) {
                int rowB = g * 16 + lr;
                bf16x8 b = *(const bf16x8*)(Bb + rowB * 128 + (byteoff ^ ((rowB & 7) << 4)));
                acc[g] = MFMA16(a, b, acc[g]);
            }
        }
        __syncthreads();  // drains vmcnt (tile kt+1 ready) + LDS reads done
    }

    // ---- epilogue: input path + cell, all in-lane ----
    __hip_bfloat16* hout = hs + (size_t)t * BATCH * HDIM;
#pragma unroll
    for (int r = 0; r < 4; ++r) {
        int row = w * 16 + lk * 4 + r;  // block-local batch row
        float xv[SDIM];
#pragma unroll
        for (int s = 0; s < SDIM; s++) xv[s] = s_inp[row * SDIM + s];
        float pre[4];
#pragma unroll
        for (int g = 0; g < 4; ++g) {
            int nloc = g * 16 + lr;
            float a = acc[g][r] + s_wq[nloc * 11 + 10];
#pragma unroll
            for (int s = 0; s < SDIM; s++) a += xv[s] * s_wq[nloc * 11 + s];
            pre[g] = a;
        }
        float ig = sigmoidf_(pre[0]);
        float fg = sigmoidf_(pre[1]);
        float gg = tanhf_(pre[2]);
        float og = sigmoidf_(pre[3]);
        size_t ci = (size_t)(m0 + row) * HDIM + h0 + lr;
        float cn = fg * c_buf[ci] + ig * gg;
        c_buf[ci] = cn;
        hout[ci] = __float2bfloat16(og * tanhf_(cn));
    }
}

// ---------------------------------------------------------------------------
// out[b,t,s] = hs[t,b,:] @ W_out + b_out  via MFMA (N padded 10->16).
// 256 blocks x 256 thr (4 waves); each wave: 2 strips of 16 rows, K=1024.
// ---------------------------------------------------------------------------
__launch_bounds__(256)
__global__ void out_mfma(const __hip_bfloat16* __restrict__ hs,
                         const __hip_bfloat16* __restrict__ wot, // [16][1024]
                         const float* __restrict__ b_out,
                         float* __restrict__ out) {
    __shared__ __align__(16) unsigned char sW[32768];
    const int tid = threadIdx.x, lane = tid & 63, wv = tid >> 6;
    const int lr = lane & 15, lk = lane >> 4;
#pragma unroll
    for (int i = 0; i < 8; i++) {
        int q = tid + i * 256;
        int row = q >> 7, col = q & 127;
        uint4 v = *(const uint4*)(wot + row * 1024 + col * 8);
        *(uint4*)(sW + row * 2048 + ((col * 16) ^ ((row & 7) << 4))) = v;
    }
    float bo = (lr < SDIM) ? b_out[lr] : 0.0f;
    __syncthreads();
    const int sw = (lr & 7) << 4;
    const int brow = lr * 2048;
#pragma unroll
    for (int s2 = 0; s2 < 2; s2++) {
        int strip = blockIdx.x * 8 + wv * 2 + s2;
        const __hip_bfloat16* Ab = hs + (size_t)(strip * 16 + lr) * 1024 + lk * 8;
        f32x4 acc = {0.f, 0.f, 0.f, 0.f};
        for (int kc = 0; kc < 32; kc++) {
            bf16x8 a = *(const bf16x8*)(Ab + kc * 32);
            bf16x8 b = *(const bf16x8*)(sW + brow + ((kc * 64 + lk * 16) ^ sw));
            acc = MFMA16(a, b, acc);
        }
        if (lr < SDIM) {
#pragma unroll
            for (int r = 0; r < 4; r++) {
                int grow = strip * 16 + lk * 4 + r;
                out[(grow & 511) * (T_STEPS * SDIM) + (grow >> 9) * SDIM + lr] = acc[r] + bo;
            }
        }
    }
}

// ---------------------------------------------------------------------------
extern "C" void kernel_launch(void* const* d_in, const int* in_sizes, int n_in,
                              void* d_out, int out_size, void* d_ws, size_t ws_size,
                              hipStream_t stream) {
    const float* inputs = (const float*)d_in[0];
    const float* W_in   = (const float*)d_in[1];
    const float* b_in   = (const float*)d_in[2];
    const float* W_ih   = (const float*)d_in[3];
    const float* W_hh   = (const float*)d_in[4];
    const float* b_ih   = (const float*)d_in[5];
    const float* b_hh   = (const float*)d_in[6];
    const float* W_out  = (const float*)d_in[7];
    const float* b_out  = (const float*)d_in[8];
    float* out = (float*)d_out;

    uint8_t* ws = (uint8_t*)d_ws;
    __hip_bfloat16* whh_bf = (__hip_bfloat16*)(ws);                       //  8 MB
    __hip_bfloat16* hs     = (__hip_bfloat16*)(ws + 8388608ull);          // 64 MB
    float*          c_buf  = (float*)(ws + 75497472ull);                  //  2 MB
    __hip_bfloat16* wot_bf = (__hip_bfloat16*)(ws + 77594624ull);         // 32 KB
    float*          Weq    = (float*)(ws + 77627392ull);                  // 160 KB
    float*          beq    = (float*)(ws + 77791232ull);                  //  16 KB

    setup_kernel<<<2048, 256, 0, stream>>>(W_hh, W_out, whh_bf, wot_bf);
    weq_kernel<<<256, 256, 0, stream>>>(W_in, W_ih, b_in, b_ih, b_hh, Weq, beq);
    t0_kernel<<<2048, 256, 0, stream>>>(inputs, Weq, beq, hs, c_buf);
    for (int t = 1; t < T_STEPS; t++)
        step_kernel<<<512, 256, 0, stream>>>(inputs, Weq, beq, whh_bf, hs, c_buf, t);
    out_mfma<<<256, 256, 0, stream>>>(hs, wot_bf, b_out, out);
}

// Round 7
// 837.869 us; speedup vs baseline: 6.0656x; 1.4687x over previous
//
#include <hip/hip_runtime.h>
#include <hip/hip_bf16.h>
#include <stdint.h>

#define T_STEPS 64
#define BATCH   512
#define SDIM    10
#define HDIM    1024
#define GDIM    4096   // 4*H

typedef __attribute__((ext_vector_type(8))) short bf16x8;
typedef __attribute__((ext_vector_type(4))) float f32x4;

#define MFMA16(a,b,c) __builtin_amdgcn_mfma_f32_16x16x32_bf16(a,b,c,0,0,0)
#define VMW(N) asm volatile("s_waitcnt vmcnt(" #N ")" ::: "memory")
#define LGKM0  asm volatile("s_waitcnt lgkmcnt(0)" ::: "memory")
#define SBAR   do { __builtin_amdgcn_s_barrier(); __builtin_amdgcn_sched_barrier(0); } while (0)

__device__ __forceinline__ float sigmoidf_(float x) { return 1.0f / (1.0f + __expf(-x)); }
__device__ __forceinline__ float tanhf_(float x) {
    x = fminf(15.0f, fmaxf(-15.0f, x));
    float e = __expf(2.0f * x);
    return (e - 1.0f) / (e + 1.0f);
}
__device__ __forceinline__ short bf16bits(float v) {
    __hip_bfloat16 hb = __float2bfloat16(v);
    return *(short*)&hb;
}

// async global->LDS, 16B/lane; LDS dest = wave-uniform base + lane*16
__device__ __forceinline__ void gload16(const void* g, void* l) {
    __builtin_amdgcn_global_load_lds(
        (const __attribute__((address_space(1))) unsigned int*)g,
        (__attribute__((address_space(3))) unsigned int*)l, 16, 0, 0);
}

// ---------------------------------------------------------------------------
// Setup: W_hh -> bf16 ([4H][H], K contiguous); W_out -> bf16 transposed+padded
// ---------------------------------------------------------------------------
__global__ void setup_kernel(const float* __restrict__ W_hh,
                             const float* __restrict__ W_out,
                             __hip_bfloat16* __restrict__ whh_bf,
                             __hip_bfloat16* __restrict__ wot_bf) {
    int idx = blockIdx.x * blockDim.x + threadIdx.x;
    int stride = gridDim.x * blockDim.x;
    for (int i = idx; i < GDIM * HDIM; i += stride)
        whh_bf[i] = __float2bfloat16(W_hh[i]);
    for (int i = idx; i < 16 * HDIM; i += stride) {
        int n = i >> 10, k = i & 1023;
        wot_bf[i] = (n < SDIM) ? __float2bfloat16(W_out[k * SDIM + n]) : __float2bfloat16(0.0f);
    }
}

// ---------------------------------------------------------------------------
// weq_bf[n][32] bf16: cols 0..9 = sum_k W_in[s][k]*W_ih[n][k]; col 10 = bias
// (b_ih+b_hh+b_in@W_ih^T); cols 11..31 = 0.  (augmented-K B operand, n-major)
// ---------------------------------------------------------------------------
__launch_bounds__(256)
__global__ void weq_kernel(const float* __restrict__ W_in,
                           const float* __restrict__ W_ih,
                           const float* __restrict__ b_in,
                           const float* __restrict__ b_ih,
                           const float* __restrict__ b_hh,
                           __hip_bfloat16* __restrict__ weq_bf) {
    __shared__ float sWin[SDIM * HDIM];  // 40 KB
    __shared__ float sbin[HDIM];
    const int tid = threadIdx.x;
    for (int i = tid; i < SDIM * HDIM; i += 256) sWin[i] = W_in[i];
    for (int i = tid; i < HDIM; i += 256) sbin[i] = b_in[i];
    __syncthreads();
    const int wv = tid >> 6, lane = tid & 63;
#pragma unroll
    for (int j = 0; j < 4; ++j) {
        int n = blockIdx.x * 16 + wv * 4 + j;
        float acc[SDIM + 1];
#pragma unroll
        for (int s = 0; s <= SDIM; s++) acc[s] = 0.0f;
        for (int it = 0; it < HDIM / 64; ++it) {
            int k = lane + it * 64;
            float wih = W_ih[n * HDIM + k];
#pragma unroll
            for (int s = 0; s < SDIM; s++) acc[s] += wih * sWin[s * HDIM + k];
            acc[SDIM] += wih * sbin[k];
        }
#pragma unroll
        for (int s = 0; s <= SDIM; s++) {
            float v = acc[s];
            for (int off = 32; off > 0; off >>= 1) v += __shfl_down(v, off);
            acc[s] = v;
        }
        if (lane == 0) {
            __hip_bfloat16 rowv[32];
#pragma unroll
            for (int s = 0; s < SDIM; s++) rowv[s] = __float2bfloat16(acc[s]);
            rowv[10] = __float2bfloat16(acc[SDIM] + b_ih[n] + b_hh[n]);
#pragma unroll
            for (int s = 11; s < 32; s++) rowv[s] = __float2bfloat16(0.0f);
#pragma unroll
            for (int q = 0; q < 4; q++)
                ((uint4*)(weq_bf + n * 32))[q] = ((uint4*)rowv)[q];
        }
    }
}

// ---------------------------------------------------------------------------
// t = 0: h_prev = 0, gates = input path only (bf16 weights, matches steps).
// ---------------------------------------------------------------------------
__launch_bounds__(256)
__global__ void t0_kernel(const float* __restrict__ inputs,
                          const __hip_bfloat16* __restrict__ weq_bf,
                          __hip_bfloat16* __restrict__ hs,
                          float* __restrict__ c_buf) {
    int gidx = blockIdx.x * 256 + threadIdx.x;
    int b = gidx >> 10, h = gidx & 1023;
    float xv[SDIM];
#pragma unroll
    for (int s = 0; s < SDIM; s++) xv[s] = inputs[b * SDIM + s];
    float pre[4];
#pragma unroll
    for (int g = 0; g < 4; ++g) {
        const __hip_bfloat16* wr = weq_bf + (size_t)(g * HDIM + h) * 32;
        float a = __bfloat162float(wr[10]);
#pragma unroll
        for (int s = 0; s < SDIM; s++) a += xv[s] * __bfloat162float(wr[s]);
        pre[g] = a;
    }
    float ig = sigmoidf_(pre[0]);
    float gg = tanhf_(pre[2]);
    float og = sigmoidf_(pre[3]);
    float cn = ig * gg;
    c_buf[gidx] = cn;
    hs[gidx] = __float2bfloat16(og * tanhf_(cn));
}

// ---------------------------------------------------------------------------
// One LSTM timestep. Block 64 batch-rows x 128 cols (32 h x 4 gates,
// gate-minor: col = hh*4+g). 256 thr = 4 waves (2m x 2n), wave tile 32x64
// -> 6 ds_read_b128 per 8 MFMA. K augmented: 1024 (W_hh) + 32 ([x|1|0]@
// [Weq|beq|0]) so the input path is one extra MFMA k-step.
// Pipeline: depth-4 LDS buffers, counted vmcnt(12) + raw s_barrier per tile
// (prefetch DMAs live across barriers; never vmcnt(0) mid-loop).
// Grid 256 = 8m x 32n, XCD-major n (W_hh stripe L2-resident per XCD).
// ---------------------------------------------------------------------------
__launch_bounds__(256, 1)
__global__ void step_kernel(const float* __restrict__ inputs,
                            const __hip_bfloat16* __restrict__ weq_bf,
                            const __hip_bfloat16* __restrict__ whh,
                            __hip_bfloat16* __restrict__ hs,
                            float* __restrict__ c_buf,
                            int t) {
    // [0:98304) 4 stage bufs x (A 8KB + B 16KB); X f32[64][128] aliases [0:32768)
    // [98304:106496) augA [64 rows][128B]; [106496:122880) augB [128 rows][128B]
    __shared__ __align__(16) unsigned char lds[122880];
    unsigned char* augA = lds + 98304;
    unsigned char* augB = lds + 106496;

    const int tid = threadIdx.x;
    const int wv = tid >> 6, lane = tid & 63;
    const int wm = wv >> 1, wn = wv & 1;
    const int lr = lane & 15, lk = lane >> 4;

    const int bid = blockIdx.x;
    const int nb = (bid & 7) * 4 + ((bid >> 3) & 3);  // XCD-major n-block
    const int mb = bid >> 5;
    const int m0 = mb * 64, h0 = nb * 32;

    const __hip_bfloat16* hprev = hs + (size_t)(t - 1) * BATCH * HDIM;

    // ---- staging sources (pre-swizzled chunk: c8 ^ (row&7)) ----
    const int srow = lane >> 3, sc8 = lane & 7;
    const __hip_bfloat16* aSrc[2]; int aDst[2];
#pragma unroll
    for (int j = 0; j < 2; j++) {
        int row = wv * 16 + j * 8 + srow;
        aSrc[j] = hprev + (size_t)(m0 + row) * HDIM + ((sc8 ^ (row & 7)) << 3);
        aDst[j] = wv * 2048 + j * 1024;
    }
    const __hip_bfloat16* bSrc[4]; int bDst[4];
#pragma unroll
    for (int j = 0; j < 4; j++) {
        int c = wv * 32 + j * 8 + srow;
        int n = (c & 3) * HDIM + h0 + (c >> 2);
        bSrc[j] = whh + (size_t)n * HDIM + ((sc8 ^ (c & 7)) << 3);
        bDst[j] = 8192 + wv * 4096 + j * 1024;
    }

    auto STAGE = [&](int kt) {
        const int base = (kt & 3) * 24576;
        const int ko = kt * 64;
        gload16(aSrc[0] + ko, lds + base + aDst[0]);
        gload16(aSrc[1] + ko, lds + base + aDst[1]);
        gload16(bSrc[0] + ko, lds + base + bDst[0]);
        gload16(bSrc[1] + ko, lds + base + bDst[1]);
        gload16(bSrc[2] + ko, lds + base + bDst[2]);
        gload16(bSrc[3] + ko, lds + base + bDst[3]);
    };

    // ---- prologue: zero augA; issue aug loads; issue 3 stage tiles ----
    *(uint4*)(augA + tid * 32) = (uint4){0, 0, 0, 0};
    *(uint4*)(augA + tid * 32 + 16) = (uint4){0, 0, 0, 0};

    float4 xv4 = {0.f, 0.f, 0.f, 0.f};
    if (tid < 160) xv4 = *(const float4*)(inputs + (size_t)(t * BATCH + m0) * SDIM + tid * 4);
    uint4 wb[2];
#pragma unroll
    for (int i = 0; i < 2; i++) {
        int q = tid + i * 256, c = q >> 2, ch = q & 3;
        int n = (c & 3) * HDIM + h0 + (c >> 2);
        wb[i] = *(const uint4*)(weq_bf + (size_t)n * 32 + ch * 8);
    }

    STAGE(0); STAGE(1); STAGE(2);   // 18 DMAs/wave in flight

    LGKM0; SBAR;  // zero-fill visible

    // augA: x (bf16) at cols 0..9, 1.0 at col 10
    if (tid < 160) {
        float xf[4] = {xv4.x, xv4.y, xv4.z, xv4.w};
#pragma unroll
        for (int q = 0; q < 4; q++) {
            int idx = tid * 4 + q, row = idx / SDIM, col = idx - row * SDIM;
            *(short*)(augA + ((row * 128 + col * 2) ^ ((row & 7) << 4))) = bf16bits(xf[q]);
        }
    }
    if (tid < 64)
        *(short*)(augA + ((tid * 128 + 20) ^ ((tid & 7) << 4))) = (short)0x3F80;
    // augB: weq rows
#pragma unroll
    for (int i = 0; i < 2; i++) {
        int q = tid + i * 256, c = q >> 2, ch = q & 3;
        *(uint4*)(augB + c * 128 + ((ch * 16) ^ ((c & 7) << 4))) = wb[i];
    }
    LGKM0; SBAR;

    // ---- row offsets for fragment reads ----
    int aro[2], asz[2], bro[4], bsz[4];
#pragma unroll
    for (int fm = 0; fm < 2; fm++) {
        int row = wm * 32 + fm * 16 + lr;
        aro[fm] = row * 128; asz[fm] = (row & 7) << 4;
    }
#pragma unroll
    for (int fn = 0; fn < 4; fn++) {
        int c = wn * 64 + fn * 16 + lr;
        bro[fn] = c * 128; bsz[fn] = (c & 7) << 4;
    }

    // ---- aug k-step (input path + bias via MFMA, acc starts at zero) ----
    f32x4 acc[2][4];
#pragma unroll
    for (int fm = 0; fm < 2; fm++)
#pragma unroll
        for (int fn = 0; fn < 4; fn++) {
            f32x4 z = {0.f, 0.f, 0.f, 0.f};
            acc[fm][fn] = z;
        }
    {
        bf16x8 a[2], b[4];
#pragma unroll
        for (int fm = 0; fm < 2; fm++)
            a[fm] = *(const bf16x8*)(augA + aro[fm] + ((lk * 16) ^ asz[fm]));
#pragma unroll
        for (int fn = 0; fn < 4; fn++)
            b[fn] = *(const bf16x8*)(augB + bro[fn] + ((lk * 16) ^ bsz[fn]));
#pragma unroll
        for (int fm = 0; fm < 2; fm++)
#pragma unroll
            for (int fn = 0; fn < 4; fn++)
                acc[fm][fn] = MFMA16(a[fm], b[fn], acc[fm][fn]);
    }

    // ---- main K-loop: 16 tiles of 64, counted-vmcnt pipeline ----
    for (int i = 0; i < 16; ++i) {
        if (i < 14)      { VMW(12); }
        else if (i == 14){ VMW(6);  }
        else             { VMW(0);  }
        SBAR;
        if (i < 13) STAGE(i + 3);
        const unsigned char* Ab = lds + (i & 3) * 24576;
        const unsigned char* Bb = Ab + 8192;
#pragma unroll
        for (int ks = 0; ks < 2; ++ks) {
            const int lo = ks * 64 + lk * 16;
            bf16x8 a[2], b[4];
#pragma unroll
            for (int fm = 0; fm < 2; fm++)
                a[fm] = *(const bf16x8*)(Ab + aro[fm] + (lo ^ asz[fm]));
#pragma unroll
            for (int fn = 0; fn < 4; fn++)
                b[fn] = *(const bf16x8*)(Bb + bro[fn] + (lo ^ bsz[fn]));
#pragma unroll
            for (int fm = 0; fm < 2; fm++)
#pragma unroll
                for (int fn = 0; fn < 4; fn++)
                    acc[fm][fn] = MFMA16(a[fm], b[fn], acc[fm][fn]);
        }
    }

    // ---- epilogue: X exchange (XOR-swizzled) + in-lane cell ----
#pragma unroll
    for (int fm = 0; fm < 2; fm++)
#pragma unroll
        for (int fn = 0; fn < 4; fn++)
#pragma unroll
            for (int r = 0; r < 4; r++) {
                int row = wm * 32 + fm * 16 + lk * 4 + r;
                int col = wn * 64 + fn * 16 + lr;
                *(float*)(lds + ((row * 512 + col * 4) ^ ((row & 7) << 4))) = acc[fm][fn][r];
            }
    LGKM0; SBAR;

    {
        const int row = tid >> 2, hh0 = (tid & 3) * 8;
        const size_t gbase = (size_t)(m0 + row) * HDIM + h0 + hh0;
        float4 c0 = *(float4*)(c_buf + gbase);
        float4 c1 = *(float4*)(c_buf + gbase + 4);
        float cold[8] = {c0.x, c0.y, c0.z, c0.w, c1.x, c1.y, c1.z, c1.w};
        float cnew[8];
        short hv[8];
#pragma unroll
        for (int j = 0; j < 8; j++) {
            float4 g4 = *(const float4*)(lds + ((row * 512 + (hh0 + j) * 16) ^ ((row & 7) << 4)));
            float ig = sigmoidf_(g4.x);
            float fg = sigmoidf_(g4.y);
            float gg = tanhf_(g4.z);
            float og = sigmoidf_(g4.w);
            float cn = fg * cold[j] + ig * gg;
            cnew[j] = cn;
            hv[j] = bf16bits(og * tanhf_(cn));
        }
        *(float4*)(c_buf + gbase) = (float4){cnew[0], cnew[1], cnew[2], cnew[3]};
        *(float4*)(c_buf + gbase + 4) = (float4){cnew[4], cnew[5], cnew[6], cnew[7]};
        *(uint4*)(hs + (size_t)t * BATCH * HDIM + gbase) = *(uint4*)hv;
    }
}

// ---------------------------------------------------------------------------
// out[b,t,s] = hs[t,b,:] @ W_out + b_out via MFMA (N padded 10->16).
// ---------------------------------------------------------------------------
__launch_bounds__(256)
__global__ void out_mfma(const __hip_bfloat16* __restrict__ hs,
                         const __hip_bfloat16* __restrict__ wot, // [16][1024]
                         const float* __restrict__ b_out,
                         float* __restrict__ out) {
    __shared__ __align__(16) unsigned char sW[32768];
    const int tid = threadIdx.x, lane = tid & 63, wv = tid >> 6;
    const int lr = lane & 15, lk = lane >> 4;
#pragma unroll
    for (int i = 0; i < 8; i++) {
        int q = tid + i * 256;
        int row = q >> 7, col = q & 127;
        uint4 v = *(const uint4*)(wot + row * 1024 + col * 8);
        *(uint4*)(sW + row * 2048 + ((col * 16) ^ ((row & 7) << 4))) = v;
    }
    float bo = (lr < SDIM) ? b_out[lr] : 0.0f;
    __syncthreads();
    const int sw = (lr & 7) << 4;
    const int brow = lr * 2048;
#pragma unroll
    for (int s2 = 0; s2 < 2; s2++) {
        int strip = blockIdx.x * 8 + wv * 2 + s2;
        const __hip_bfloat16* Ab = hs + (size_t)(strip * 16 + lr) * 1024 + lk * 8;
        f32x4 acc = {0.f, 0.f, 0.f, 0.f};
        for (int kc = 0; kc < 32; kc++) {
            bf16x8 a = *(const bf16x8*)(Ab + kc * 32);
            bf16x8 b = *(const bf16x8*)(sW + brow + ((kc * 64 + lk * 16) ^ sw));
            acc = MFMA16(a, b, acc);
        }
        if (lr < SDIM) {
#pragma unroll
            for (int r = 0; r < 4; r++) {
                int grow = strip * 16 + lk * 4 + r;
                out[(grow & 511) * (T_STEPS * SDIM) + (grow >> 9) * SDIM + lr] = acc[r] + bo;
            }
        }
    }
}

// ---------------------------------------------------------------------------
extern "C" void kernel_launch(void* const* d_in, const int* in_sizes, int n_in,
                              void* d_out, int out_size, void* d_ws, size_t ws_size,
                              hipStream_t stream) {
    const float* inputs = (const float*)d_in[0];
    const float* W_in   = (const float*)d_in[1];
    const float* b_in   = (const float*)d_in[2];
    const float* W_ih   = (const float*)d_in[3];
    const float* W_hh   = (const float*)d_in[4];
    const float* b_ih   = (const float*)d_in[5];
    const float* b_hh   = (const float*)d_in[6];
    const float* W_out  = (const float*)d_in[7];
    const float* b_out  = (const float*)d_in[8];
    float* out = (float*)d_out;

    uint8_t* ws = (uint8_t*)d_ws;
    __hip_bfloat16* whh_bf = (__hip_bfloat16*)(ws);                    //  8 MB
    __hip_bfloat16* hs     = (__hip_bfloat16*)(ws + 8388608ull);       // 64 MB
    float*          c_buf  = (float*)(ws + 75497472ull);               //  2 MB
    __hip_bfloat16* wot_bf = (__hip_bfloat16*)(ws + 77594624ull);      // 32 KB
    __hip_bfloat16* weq_bf = (__hip_bfloat16*)(ws + 77660160ull);      // 256 KB

    setup_kernel<<<2048, 256, 0, stream>>>(W_hh, W_out, whh_bf, wot_bf);
    weq_kernel<<<256, 256, 0, stream>>>(W_in, W_ih, b_in, b_ih, b_hh, weq_bf);
    t0_kernel<<<2048, 256, 0, stream>>>(inputs, weq_bf, hs, c_buf);
    for (int t = 1; t < T_STEPS; t++)
        step_kernel<<<256, 256, 0, stream>>>(inputs, weq_bf, whh_bf, hs, c_buf, t);
    out_mfma<<<256, 256, 0, stream>>>(hs, wot_bf, b_out, out);
}

// Round 9
// 697.752 us; speedup vs baseline: 7.2836x; 1.2008x over previous
//
#include <hip/hip_runtime.h>
#include <hip/hip_bf16.h>
#include <stdint.h>

#define T_STEPS 64
#define BATCH   512
#define SDIM    10
#define HDIM    1024
#define GDIM    4096   // 4*H

typedef __attribute__((ext_vector_type(8))) short bf16x8;
typedef __attribute__((ext_vector_type(4))) float f32x4;

#define MFMA16(a,b,c) __builtin_amdgcn_mfma_f32_16x16x32_bf16(a,b,c,0,0,0)
#define VMW(N) asm volatile("s_waitcnt vmcnt(" #N ")" ::: "memory")
#define LGKM0  asm volatile("s_waitcnt lgkmcnt(0)" ::: "memory")
#define SBAR   do { __builtin_amdgcn_s_barrier(); __builtin_amdgcn_sched_barrier(0); } while (0)

__device__ __forceinline__ float sigmoidf_(float x) { return 1.0f / (1.0f + __expf(-x)); }
__device__ __forceinline__ float tanhf_(float x) {
    x = fminf(15.0f, fmaxf(-15.0f, x));
    float e = __expf(2.0f * x);
    return (e - 1.0f) / (e + 1.0f);
}
__device__ __forceinline__ short bf16bits(float v) {
    __hip_bfloat16 hb = __float2bfloat16(v);
    return *(short*)&hb;
}

// async global->LDS, 16B/lane; LDS dest = wave-uniform base + lane*16
__device__ __forceinline__ void gload16(const void* g, void* l) {
    __builtin_amdgcn_global_load_lds(
        (const __attribute__((address_space(1))) unsigned int*)g,
        (__attribute__((address_space(3))) unsigned int*)l, 16, 0, 0);
}

// ---------------------------------------------------------------------------
// Setup: W_hh -> bf16 ([4H][H], K contiguous); W_out -> bf16 transposed+padded
// ---------------------------------------------------------------------------
__global__ void setup_kernel(const float* __restrict__ W_hh,
                             const float* __restrict__ W_out,
                             __hip_bfloat16* __restrict__ whh_bf,
                             __hip_bfloat16* __restrict__ wot_bf) {
    int idx = blockIdx.x * blockDim.x + threadIdx.x;
    int stride = gridDim.x * blockDim.x;
    for (int i = idx; i < GDIM * HDIM; i += stride)
        whh_bf[i] = __float2bfloat16(W_hh[i]);
    for (int i = idx; i < 16 * HDIM; i += stride) {
        int n = i >> 10, k = i & 1023;
        wot_bf[i] = (n < SDIM) ? __float2bfloat16(W_out[k * SDIM + n]) : __float2bfloat16(0.0f);
    }
}

// ---------------------------------------------------------------------------
// weq_bf[n][32] bf16: cols 0..9 = sum_k W_in[s][k]*W_ih[n][k]; col 10 = bias
// (b_ih+b_hh+b_in@W_ih^T); cols 11..31 = 0.  (augmented-K B operand, n-major)
// ---------------------------------------------------------------------------
__launch_bounds__(256)
__global__ void weq_kernel(const float* __restrict__ W_in,
                           const float* __restrict__ W_ih,
                           const float* __restrict__ b_in,
                           const float* __restrict__ b_ih,
                           const float* __restrict__ b_hh,
                           __hip_bfloat16* __restrict__ weq_bf) {
    __shared__ float sWin[SDIM * HDIM];  // 40 KB
    __shared__ float sbin[HDIM];
    const int tid = threadIdx.x;
    for (int i = tid; i < SDIM * HDIM; i += 256) sWin[i] = W_in[i];
    for (int i = tid; i < HDIM; i += 256) sbin[i] = b_in[i];
    __syncthreads();
    const int wv = tid >> 6, lane = tid & 63;
#pragma unroll
    for (int j = 0; j < 4; ++j) {
        int n = blockIdx.x * 16 + wv * 4 + j;
        float acc[SDIM + 1];
#pragma unroll
        for (int s = 0; s <= SDIM; s++) acc[s] = 0.0f;
        for (int it = 0; it < HDIM / 64; ++it) {
            int k = lane + it * 64;
            float wih = W_ih[n * HDIM + k];
#pragma unroll
            for (int s = 0; s < SDIM; s++) acc[s] += wih * sWin[s * HDIM + k];
            acc[SDIM] += wih * sbin[k];
        }
#pragma unroll
        for (int s = 0; s <= SDIM; s++) {
            float v = acc[s];
            for (int off = 32; off > 0; off >>= 1) v += __shfl_down(v, off);
            acc[s] = v;
        }
        if (lane == 0) {
            __hip_bfloat16 rowv[32];
#pragma unroll
            for (int s = 0; s < SDIM; s++) rowv[s] = __float2bfloat16(acc[s]);
            rowv[10] = __float2bfloat16(acc[SDIM] + b_ih[n] + b_hh[n]);
#pragma unroll
            for (int s = 11; s < 32; s++) rowv[s] = __float2bfloat16(0.0f);
#pragma unroll
            for (int q = 0; q < 4; q++)
                ((uint4*)(weq_bf + n * 32))[q] = ((uint4*)rowv)[q];
        }
    }
}

// ---------------------------------------------------------------------------
// t = 0: h_prev = 0, gates = input path only (bf16 weights, matches steps).
// ---------------------------------------------------------------------------
__launch_bounds__(256)
__global__ void t0_kernel(const float* __restrict__ inputs,
                          const __hip_bfloat16* __restrict__ weq_bf,
                          __hip_bfloat16* __restrict__ hs,
                          float* __restrict__ c_buf) {
    int gidx = blockIdx.x * 256 + threadIdx.x;
    int b = gidx >> 10, h = gidx & 1023;
    float xv[SDIM];
#pragma unroll
    for (int s = 0; s < SDIM; s++) xv[s] = inputs[b * SDIM + s];
    float pre[4];
#pragma unroll
    for (int g = 0; g < 4; ++g) {
        const __hip_bfloat16* wr = weq_bf + (size_t)(g * HDIM + h) * 32;
        float a = __bfloat162float(wr[10]);
#pragma unroll
        for (int s = 0; s < SDIM; s++) a += xv[s] * __bfloat162float(wr[s]);
        pre[g] = a;
    }
    float ig = sigmoidf_(pre[0]);
    float gg = tanhf_(pre[2]);
    float og = sigmoidf_(pre[3]);
    float cn = ig * gg;
    c_buf[gidx] = cn;
    hs[gidx] = __float2bfloat16(og * tanhf_(cn));
}

// ---------------------------------------------------------------------------
// One LSTM timestep. Block 64 batch-rows x 128 cols (32 h x 4 gates,
// gate-minor col = hh*4+g). 512 thr = 8 waves (2m x 4n), wave tile 32x32
// (2 waves/SIMD -> stall overlap). K augmented: 1024 + 32 ([x|1|0]@[Weq|beq]).
// BK=128 intervals: 8 sync points; depth-3 48KB LDS buffers (144 KB total,
// aug aliased in buf2, X-exchange aliased in buf0). Counted vmcnt(6) steady,
// vmcnt(0) only at last interval. 256B LDS rows, chunk ^= row&15 swizzle
// (pre-swizzled DMA source, same involution on reads).
// Grid 256 = 8m x 32n, XCD-major n (W_hh stripe L2-resident per XCD).
// ---------------------------------------------------------------------------
__launch_bounds__(512, 1)
__global__ void step_kernel(const float* __restrict__ inputs,
                            const __hip_bfloat16* __restrict__ weq_bf,
                            const __hip_bfloat16* __restrict__ whh,
                            __hip_bfloat16* __restrict__ hs,
                            float* __restrict__ c_buf,
                            int t) {
    // 3 bufs x 49152 (A [64][256B] + B [128][256B]); X f32[64][128] aliases buf0;
    // augA [64][128B] + augB [128][128B] alias buf2 ([98304..122880)).
    __shared__ __align__(16) unsigned char lds[147456];
    unsigned char* augA = lds + 98304;
    unsigned char* augB = lds + 106496;

    const int tid = threadIdx.x;
    const int wv = tid >> 6, lane = tid & 63;
    const int wm = wv >> 2, wn = wv & 3;   // 2m x 4n
    const int lr = lane & 15, lk = lane >> 4;

    const int bid = blockIdx.x;
    const int nb = (bid & 7) * 4 + ((bid >> 3) & 3);  // XCD-major n-block
    const int mb = bid >> 5;
    const int m0 = mb * 64, h0 = nb * 32;

    const __hip_bfloat16* hprev = hs + (size_t)(t - 1) * BATCH * HDIM;

    // ---- staging sources (pre-swizzled chunk: phys = lch ^ (row&15)) ----
    const int lrow = lane >> 4;   // 0..3 row within one gload
    const int lch  = lane & 15;   // phys 16B chunk
    const __hip_bfloat16* aS[2]; int aD[2];
#pragma unroll
    for (int j = 0; j < 2; j++) {
        int idx = wv * 2 + j;           // 0..15
        int row = idx * 4 + lrow;       // 0..63
        int ch  = lch ^ (row & 15);
        aS[j] = hprev + (size_t)(m0 + row) * HDIM + ch * 8;
        aD[j] = idx * 1024;
    }
    const __hip_bfloat16* bS[4]; int bD[4];
#pragma unroll
    for (int j = 0; j < 4; j++) {
        int idx = wv * 4 + j;           // 0..31
        int c   = idx * 4 + lrow;       // 0..127 (gate-minor col)
        int n   = (c & 3) * HDIM + h0 + (c >> 2);
        int ch  = lch ^ (c & 15);
        bS[j] = whh + (size_t)n * HDIM + ch * 8;
        bD[j] = 16384 + idx * 1024;
    }

    auto STAGE = [&](int kt) {
        const int base = (kt % 3) * 49152;
        const int ko = kt * 128;
        gload16(aS[0] + ko, lds + base + aD[0]);
        gload16(aS[1] + ko, lds + base + aD[1]);
        gload16(bS[0] + ko, lds + base + bD[0]);
        gload16(bS[1] + ko, lds + base + bD[1]);
        gload16(bS[2] + ko, lds + base + bD[2]);
        gload16(bS[3] + ko, lds + base + bD[3]);
    };

    // ---- prologue: zero augA; issue aug global loads; stage intervals 0,1 ----
    *(uint4*)(augA + tid * 16) = (uint4){0, 0, 0, 0};   // 512*16 = 8 KB

    float4 xv4 = {0.f, 0.f, 0.f, 0.f};
    if (tid < 160) xv4 = *(const float4*)(inputs + (size_t)(t * BATCH + m0) * SDIM + tid * 4);
    const int wc = tid >> 2, wch = tid & 3;             // augB row / chunk
    const int wn_idx = (wc & 3) * HDIM + h0 + (wc >> 2);
    uint4 wb = *(const uint4*)(weq_bf + (size_t)wn_idx * 32 + wch * 8);

    STAGE(0); STAGE(1);   // 12 DMAs/wave in flight

    LGKM0; SBAR;  // zero-fill visible

    // augA: x (bf16) at cols 0..9, 1.0 at col 10 (swizzled 128B rows)
    if (tid < 160) {
        float xf[4] = {xv4.x, xv4.y, xv4.z, xv4.w};
#pragma unroll
        for (int q = 0; q < 4; q++) {
            int idx = tid * 4 + q, row = idx / SDIM, col = idx - row * SDIM;
            *(short*)(augA + ((row * 128 + col * 2) ^ ((row & 7) << 4))) = bf16bits(xf[q]);
        }
    }
    if (tid < 64)
        *(short*)(augA + ((tid * 128 + 20) ^ ((tid & 7) << 4))) = (short)0x3F80;
    // augB: weq rows (4 chunks per 128B row)
    *(uint4*)(augB + wc * 128 + ((wch * 16) ^ ((wc & 7) << 4))) = wb;
    LGKM0; SBAR;

    // ---- fragment read offsets (main: 256B rows, swz = lr<<4) ----
    int aro[2], bro[2];
#pragma unroll
    for (int fm = 0; fm < 2; fm++) aro[fm] = (wm * 32 + fm * 16 + lr) * 256;
#pragma unroll
    for (int fn = 0; fn < 2; fn++) bro[fn] = (wn * 32 + fn * 16 + lr) * 256 + 16384;
    const int swz = lr << 4;

    // ---- aug k-step (input path + bias via MFMA; 128B rows, swz row&7) ----
    f32x4 acc[2][2];
#pragma unroll
    for (int fm = 0; fm < 2; fm++)
#pragma unroll
        for (int fn = 0; fn < 2; fn++) {
            f32x4 z = {0.f, 0.f, 0.f, 0.f};
            acc[fm][fn] = z;
        }
    {
        bf16x8 a[2], b[2];
#pragma unroll
        for (int fm = 0; fm < 2; fm++) {
            int row = wm * 32 + fm * 16 + lr;
            a[fm] = *(const bf16x8*)(augA + row * 128 + ((lk * 16) ^ ((row & 7) << 4)));
        }
#pragma unroll
        for (int fn = 0; fn < 2; fn++) {
            int c = wn * 32 + fn * 16 + lr;
            b[fn] = *(const bf16x8*)(augB + c * 128 + ((lk * 16) ^ ((c & 7) << 4)));
        }
#pragma unroll
        for (int fm = 0; fm < 2; fm++)
#pragma unroll
            for (int fn = 0; fn < 2; fn++)
                acc[fm][fn] = MFMA16(a[fm], b[fn], acc[fm][fn]);
    }
    LGKM0;  // retire aug ds_reads before any wave can pass i=0 barrier
            // and issue STAGE(2), which overwrites the aug region (buf2 alias)

    // ---- main K-loop: 8 intervals of 128, counted-vmcnt depth-3 pipeline ----
#pragma unroll
    for (int i = 0; i < 8; ++i) {
        if (i < 7) { VMW(6); } else { VMW(0); }
        SBAR;
        if (i < 6) STAGE(i + 2);
        const unsigned char* Ab = lds + (i % 3) * 49152;
        const unsigned char* Bb = Ab;  // bro includes +16384
#pragma unroll
        for (int ks = 0; ks < 4; ++ks) {
            const int lo = ks * 64 + lk * 16;
            bf16x8 a[2], b[2];
#pragma unroll
            for (int fm = 0; fm < 2; fm++)
                a[fm] = *(const bf16x8*)(Ab + aro[fm] + (lo ^ swz));
#pragma unroll
            for (int fn = 0; fn < 2; fn++)
                b[fn] = *(const bf16x8*)(Bb + bro[fn] + (lo ^ swz));
#pragma unroll
            for (int fm = 0; fm < 2; fm++)
#pragma unroll
                for (int fn = 0; fn < 2; fn++)
                    acc[fm][fn] = MFMA16(a[fm], b[fn], acc[fm][fn]);
        }
    }

    // ---- epilogue: X exchange (XOR-swizzled f32 [64][128] in buf0) ----
#pragma unroll
    for (int fm = 0; fm < 2; fm++)
#pragma unroll
        for (int fn = 0; fn < 2; fn++)
#pragma unroll
            for (int r = 0; r < 4; r++) {
                int row = wm * 32 + fm * 16 + lk * 4 + r;
                int col = wn * 32 + fn * 16 + lr;
                *(float*)(lds + ((row * 512 + col * 4) ^ ((row & 7) << 4))) = acc[fm][fn][r];
            }
    LGKM0; SBAR;

    {
        const int row = tid >> 3, hq = tid & 7;   // 4 hh per thread
        const size_t gbase = (size_t)(m0 + row) * HDIM + h0 + hq * 4;
        float4 cold = *(float4*)(c_buf + gbase);
        float cget[4] = {cold.x, cold.y, cold.z, cold.w};
        float cnew[4];
        short hv[4];
#pragma unroll
        for (int q = 0; q < 4; q++) {
            int hh = hq * 4 + q;
            float4 g4 = *(const float4*)(lds + ((row * 512 + hh * 16) ^ ((row & 7) << 4)));
            float ig = sigmoidf_(g4.x);
            float fg = sigmoidf_(g4.y);
            float gg = tanhf_(g4.z);
            float og = sigmoidf_(g4.w);
            float cn = fg * cget[q] + ig * gg;
            cnew[q] = cn;
            hv[q] = bf16bits(og * tanhf_(cn));
        }
        *(float4*)(c_buf + gbase) = (float4){cnew[0], cnew[1], cnew[2], cnew[3]};
        *(uint2*)(hs + (size_t)t * BATCH * HDIM + gbase) = *(uint2*)hv;
    }
}

// ---------------------------------------------------------------------------
// out[b,t,s] = hs[t,b,:] @ W_out + b_out via MFMA (N padded 10->16).
// ---------------------------------------------------------------------------
__launch_bounds__(256)
__global__ void out_mfma(const __hip_bfloat16* __restrict__ hs,
                         const __hip_bfloat16* __restrict__ wot, // [16][1024]
                         const float* __restrict__ b_out,
                         float* __restrict__ out) {
    __shared__ __align__(16) unsigned char sW[32768];
    const int tid = threadIdx.x, lane = tid & 63, wv = tid >> 6;
    const int lr = lane & 15, lk = lane >> 4;
#pragma unroll
    for (int i = 0; i < 8; i++) {
        int q = tid + i * 256;
        int row = q >> 7, col = q & 127;
        uint4 v = *(const uint4*)(wot + row * 1024 + col * 8);
        *(uint4*)(sW + row * 2048 + ((col * 16) ^ ((row & 7) << 4))) = v;
    }
    float bo = (lr < SDIM) ? b_out[lr] : 0.0f;
    __syncthreads();
    const int sw = (lr & 7) << 4;
    const int brow = lr * 2048;
#pragma unroll
    for (int s2 = 0; s2 < 2; s2++) {
        int strip = blockIdx.x * 8 + wv * 2 + s2;
        const __hip_bfloat16* Ab = hs + (size_t)(strip * 16 + lr) * 1024 + lk * 8;
        f32x4 acc = {0.f, 0.f, 0.f, 0.f};
        for (int kc = 0; kc < 32; kc++) {
            bf16x8 a = *(const bf16x8*)(Ab + kc * 32);
            bf16x8 b = *(const bf16x8*)(sW + brow + ((kc * 64 + lk * 16) ^ sw));
            acc = MFMA16(a, b, acc);
        }
        if (lr < SDIM) {
#pragma unroll
            for (int r = 0; r < 4; r++) {
                int grow = strip * 16 + lk * 4 + r;
                out[(grow & 511) * (T_STEPS * SDIM) + (grow >> 9) * SDIM + lr] = acc[r] + bo;
            }
        }
    }
}

// ---------------------------------------------------------------------------
extern "C" void kernel_launch(void* const* d_in, const int* in_sizes, int n_in,
                              void* d_out, int out_size, void* d_ws, size_t ws_size,
                              hipStream_t stream) {
    const float* inputs = (const float*)d_in[0];
    const float* W_in   = (const float*)d_in[1];
    const float* b_in   = (const float*)d_in[2];
    const float* W_ih   = (const float*)d_in[3];
    const float* W_hh   = (const float*)d_in[4];
    const float* b_ih   = (const float*)d_in[5];
    const float* b_hh   = (const float*)d_in[6];
    const float* W_out  = (const float*)d_in[7];
    const float* b_out  = (const float*)d_in[8];
    float* out = (float*)d_out;

    uint8_t* ws = (uint8_t*)d_ws;
    __hip_bfloat16* whh_bf = (__hip_bfloat16*)(ws);                    //  8 MB
    __hip_bfloat16* hs     = (__hip_bfloat16*)(ws + 8388608ull);       // 64 MB
    float*          c_buf  = (float*)(ws + 75497472ull);               //  2 MB
    __hip_bfloat16* wot_bf = (__hip_bfloat16*)(ws + 77594624ull);      // 32 KB
    __hip_bfloat16* weq_bf = (__hip_bfloat16*)(ws + 77660160ull);      // 256 KB

    setup_kernel<<<2048, 256, 0, stream>>>(W_hh, W_out, whh_bf, wot_bf);
    weq_kernel<<<256, 256, 0, stream>>>(W_in, W_ih, b_in, b_ih, b_hh, weq_bf);
    t0_kernel<<<2048, 256, 0, stream>>>(inputs, weq_bf, hs, c_buf);
    for (int t = 1; t < T_STEPS; t++)
        step_kernel<<<256, 512, 0, stream>>>(inputs, weq_bf, whh_bf, hs, c_buf, t);
    out_mfma<<<256, 256, 0, stream>>>(hs, wot_bf, b_out, out);
}